// Round 1
// baseline (3924.997 us; speedup 1.0000x reference)
//
#include <hip/hip_runtime.h>

// 400-step 2D diffusion stencil, H x H fp32, Dirichlet (zero) boundary.
// u_{t+1} = mask * (u_t + 0.225 * lap5(u_t) + 1e-7 * a)
// Step 0 reads u0 directly (its boundary is NONZERO and feeds the first
// Laplacian — mask is applied only to outputs). Ping-pong: even steps write
// ws, odd steps write d_out; step 399 (odd) lands in d_out.

#define HH 1501
#define NUM_T 400
#define STEP_PARAM 0.225f
#define DT 1e-7f

__global__ __launch_bounds__(256) void furnace_step(
    const float* __restrict__ uin,
    const float* __restrict__ a,
    float* __restrict__ uout)
{
    const int x = blockIdx.x * 256 + threadIdx.x;
    const int y = blockIdx.y;
    if (x >= HH) return;
    const int idx = y * HH + x;

    if (x == 0 || x == HH - 1 || y == 0 || y == HH - 1) {
        uout[idx] = 0.0f;   // Dirichlet mask on the output
        return;
    }

    const float c = uin[idx];
    const float lap = uin[idx - 1] + uin[idx + 1]
                    + uin[idx - HH] + uin[idx + HH]
                    - 4.0f * c;
    uout[idx] = c + STEP_PARAM * lap + DT * a[idx];
}

extern "C" void kernel_launch(void* const* d_in, const int* in_sizes, int n_in,
                              void* d_out, int out_size, void* d_ws, size_t ws_size,
                              hipStream_t stream)
{
    const float* u0 = (const float*)d_in[0];
    const float* a  = (const float*)d_in[1];
    float* out = (float*)d_out;
    float* ws  = (float*)d_ws;   // one H*H fp32 buffer (9.01 MB)

    dim3 block(256, 1, 1);
    dim3 grid((HH + 255) / 256, HH, 1);

    const float* src = u0;
    for (int t = 0; t < NUM_T; ++t) {
        float* dst = (t & 1) ? out : ws;   // odd -> d_out; t=399 is odd
        furnace_step<<<grid, block, 0, stream>>>(src, a, dst);
        src = dst;
    }
}